// Round 7
// baseline (477.674 us; speedup 1.0000x reference)
//
#include <hip/hip_runtime.h>
#include <hip/hip_fp16.h>
#include <math.h>

#define Bdim 4
#define Lseq 4096
#define INDIM 512
#define DH 64
#define OUTD 512
#define SCALE 0.125f
#define KSPL 8
#define QSPL 8
#define BL (Bdim * Lseq)

typedef _Float16 f16;
typedef _Float16 h8 __attribute__((ext_vector_type(8)));
typedef _Float16 h4 __attribute__((ext_vector_type(4)));
typedef float f4 __attribute__((ext_vector_type(4)));

#define MFMA(a, b, c) __builtin_amdgcn_mfma_f32_16x16x32_f16(a, b, c, 0, 0, 0)

// ------ W pre-transpose + f16 hi/lo split: Wq/Wk/Wv -> [mat][d][k]; Wo -> [o][d] ------
__global__ __launch_bounds__(256) void wtrans(const float* __restrict__ Wq,
                                              const float* __restrict__ Wk,
                                              const float* __restrict__ Wv,
                                              const float* __restrict__ Wo,
                                              f16* __restrict__ whi,
                                              f16* __restrict__ wlo,
                                              f16* __restrict__ woth,
                                              f16* __restrict__ wotl) {
    __shared__ float tile[64 * 68];
    int t = threadIdx.x;
    if (blockIdx.y < 3) {
        int kt = blockIdx.x * 64;
        const float* W = (blockIdx.y == 0) ? Wq : (blockIdx.y == 1) ? Wk : Wv;
        {
            int r = t >> 2, c4 = (t & 3) * 16;
            const float4* src = (const float4*)(W + (size_t)(kt + r) * DH + c4);
#pragma unroll
            for (int i = 0; i < 4; ++i)
                *(float4*)(tile + r * 68 + c4 + 4 * i) = src[i];
        }
        __syncthreads();
        {
            int d = t >> 2, k8 = (t & 3) * 16;
            h8 hi0, hi1, lo0, lo1;
#pragma unroll
            for (int j = 0; j < 8; ++j) {
                float v0 = tile[(k8 + j) * 68 + d];
                float v1 = tile[(k8 + 8 + j) * 68 + d];
                f16 h0 = (f16)v0, h1 = (f16)v1;
                hi0[j] = h0; lo0[j] = (f16)(v0 - (float)h0);
                hi1[j] = h1; lo1[j] = (f16)(v1 - (float)h1);
            }
            size_t base = ((size_t)blockIdx.y * DH + d) * INDIM + kt + k8;
            *(h8*)(whi + base) = hi0;
            *(h8*)(whi + base + 8) = hi1;
            *(h8*)(wlo + base) = lo0;
            *(h8*)(wlo + base + 8) = lo1;
        }
    } else {
        // Wo [64 d][512 o] -> WoT hi/lo [o][d], o-chunk = blockIdx.x*64
        int o0 = blockIdx.x * 64;
        {
            int d = t >> 2, o4 = (t & 3) * 16;
            const float4* src = (const float4*)(Wo + (size_t)d * OUTD + o0 + o4);
#pragma unroll
            for (int i = 0; i < 4; ++i)
                *(float4*)(tile + d * 68 + o4 + 4 * i) = src[i];
        }
        __syncthreads();
        {
            int o = t >> 2, d8 = (t & 3) * 16;
            h8 hi0, hi1, lo0, lo1;
#pragma unroll
            for (int j = 0; j < 8; ++j) {
                float v0 = tile[(d8 + j) * 68 + o];
                float v1 = tile[(d8 + 8 + j) * 68 + o];
                f16 h0 = (f16)v0, h1 = (f16)v1;
                hi0[j] = h0; lo0[j] = (f16)(v0 - (float)h0);
                hi1[j] = h1; lo1[j] = (f16)(v1 - (float)h1);
            }
            size_t base = (size_t)(o0 + o) * DH + d8;
            *(h8*)(woth + base) = hi0;
            *(h8*)(woth + base + 8) = hi1;
            *(h8*)(wotl + base) = lo0;
            *(h8*)(wotl + base + 8) = lo1;
        }
    }
}

// ---------------- fused q/k/v projection via split-precision f16 MFMA ----------
__global__ __launch_bounds__(256) void proj_qkv(const float* __restrict__ x,
                                                const f16* __restrict__ whi,
                                                const f16* __restrict__ wlo,
                                                const float* __restrict__ bq,
                                                const float* __restrict__ bk,
                                                const float* __restrict__ bv,
                                                f16* __restrict__ qh,
                                                f16* __restrict__ kh,
                                                f16* __restrict__ vt) {
    __shared__ __align__(16) f16 xh[64 * 72];
    __shared__ __align__(16) f16 xl[64 * 72];
    __shared__ __align__(16) f16 wl[6][64 * 72];   // [mat*2 + hilo][d][k]
    int t = threadIdx.x;
    int w = t >> 6, lane = t & 63;
    int l15 = lane & 15, quad = lane >> 4;
    size_t row0 = (size_t)blockIdx.x * 64;

    int xr = t >> 2, xkq = (t & 3) * 16;
    int wd = t >> 2, wko = (t & 3) * 16;

    f4 acc[3][4];
#pragma unroll
    for (int m = 0; m < 3; ++m)
#pragma unroll
        for (int nt = 0; nt < 4; ++nt) acc[m][nt] = (f4){0.f, 0.f, 0.f, 0.f};

    f4 xs[4];
    h8 wsr[12];

#define PROJ_ISSUE(kc)                                                             \
    {                                                                              \
        const f4* xsrc = (const f4*)(x + (row0 + xr) * INDIM + (kc) + xkq);        \
        _Pragma("unroll") for (int i = 0; i < 4; ++i) xs[i] = xsrc[i];             \
        _Pragma("unroll") for (int p = 0; p < 6; ++p) {                            \
            const f16* src = ((p & 1) ? wlo : whi) +                               \
                             ((size_t)(p >> 1) * DH + wd) * INDIM + (kc) + wko;    \
            wsr[p * 2] = *(const h8*)src;                                          \
            wsr[p * 2 + 1] = *(const h8*)(src + 8);                                \
        }                                                                          \
    }

#define PROJ_COMMIT()                                                              \
    {                                                                              \
        h8 hi0, hi1, lo0, lo1;                                                     \
        _Pragma("unroll") for (int j = 0; j < 8; ++j) {                            \
            float v0 = ((const float*)xs)[j];                                      \
            float v1 = ((const float*)xs)[8 + j];                                  \
            f16 h0 = (f16)v0, h1 = (f16)v1;                                        \
            hi0[j] = h0; lo0[j] = (f16)(v0 - (float)h0);                           \
            hi1[j] = h1; lo1[j] = (f16)(v1 - (float)h1);                           \
        }                                                                          \
        *(h8*)(xh + xr * 72 + xkq) = hi0;                                          \
        *(h8*)(xh + xr * 72 + xkq + 8) = hi1;                                      \
        *(h8*)(xl + xr * 72 + xkq) = lo0;                                          \
        *(h8*)(xl + xr * 72 + xkq + 8) = lo1;                                      \
        _Pragma("unroll") for (int p = 0; p < 6; ++p) {                            \
            *(h8*)(wl[p] + wd * 72 + wko) = wsr[p * 2];                            \
            *(h8*)(wl[p] + wd * 72 + wko + 8) = wsr[p * 2 + 1];                    \
        }                                                                          \
    }

    PROJ_ISSUE(0);
    PROJ_COMMIT();
    __syncthreads();

    int arow = w * 16 + l15;
    for (int it = 0; it < 8; ++it) {
        if (it < 7) PROJ_ISSUE((it + 1) * 64);

        h8 ah0 = *(const h8*)(xh + arow * 72 + quad * 8);
        h8 ah1 = *(const h8*)(xh + arow * 72 + 32 + quad * 8);
        h8 al0 = *(const h8*)(xl + arow * 72 + quad * 8);
        h8 al1 = *(const h8*)(xl + arow * 72 + 32 + quad * 8);
#pragma unroll
        for (int m = 0; m < 3; ++m) {
            const f16* bh = wl[m * 2];
            const f16* bl = wl[m * 2 + 1];
#pragma unroll
            for (int nt = 0; nt < 4; ++nt) {
                int d = nt * 16 + l15;
                h8 bh0 = *(const h8*)(bh + d * 72 + quad * 8);
                h8 bh1 = *(const h8*)(bh + d * 72 + 32 + quad * 8);
                h8 bl0 = *(const h8*)(bl + d * 72 + quad * 8);
                h8 bl1 = *(const h8*)(bl + d * 72 + 32 + quad * 8);
                f4 c = acc[m][nt];
                c = MFMA(ah0, bh0, c);
                c = MFMA(ah1, bh1, c);
                c = MFMA(al0, bh0, c);
                c = MFMA(al1, bh1, c);
                c = MFMA(ah0, bl0, c);
                c = MFMA(ah1, bl1, c);
                acc[m][nt] = c;
            }
        }
        __syncthreads();
        if (it < 7) PROJ_COMMIT();
        __syncthreads();
    }

    int b = (int)(row0 >> 12);
    int kr0 = ((int)row0 & (Lseq - 1)) + w * 16 + quad * 4;
#pragma unroll
    for (int nt = 0; nt < 4; ++nt) {
        int d = nt * 16 + l15;
        float bqv = bq[d], bkv = bk[d], bvv = bv[d];
#pragma unroll
        for (int reg = 0; reg < 4; ++reg) {
            size_t r = row0 + w * 16 + quad * 4 + reg;
            qh[r * DH + d] = (f16)((acc[0][nt][reg] + bqv) * SCALE);
            kh[r * DH + d] = (f16)(acc[1][nt][reg] + bkv);
        }
        h4 pv;
#pragma unroll
        for (int reg = 0; reg < 4; ++reg) pv[reg] = (f16)(acc[2][nt][reg] + bvv);
        *(h4*)(vt + ((size_t)b * DH + d) * Lseq + kr0) = pv;
    }
#undef PROJ_ISSUE
#undef PROJ_COMMIT
}

// ---------------- pass 1: column sums of exp(s) via MFMA (D = K·Q^T) ------------
__global__ __launch_bounds__(256) void col_stats(const f16* __restrict__ qh,
                                                 const f16* __restrict__ kh,
                                                 float* __restrict__ lsum) {
    __shared__ __align__(16) f16 qlds[2][64 * 72];
    int t = threadIdx.x;
    int w = t >> 6, lane = t & 63;
    int l15 = lane & 15, quad = lane >> 4;
    int b = blockIdx.y;
    int kblk = blockIdx.x * 128;
    int qbase = blockIdx.z * (Lseq / QSPL);

    h8 a[2][2];
#pragma unroll
    for (int kt = 0; kt < 2; ++kt) {
        const h8* kr = (const h8*)(kh + ((size_t)b * Lseq + kblk + w * 32 + kt * 16 + l15) * DH + quad * 8);
        a[kt][0] = kr[0];
        a[kt][1] = kr[4];
    }
    float lp[2][4] = {};

#pragma unroll
    for (int i = 0; i < 2; ++i) {
        int lin = i * 256 + t;
        int row = lin >> 3, c8 = lin & 7;
        *(h8*)(qlds[0] + row * 72 + c8 * 8) =
            *(const h8*)(qh + ((size_t)b * Lseq + qbase + row) * DH + c8 * 8);
    }
    __syncthreads();

    for (int it = 0; it < (Lseq / QSPL) / 64; ++it) {
        h8 s0, s1;
        int r0_ = 0, c0_ = 0, r1_ = 0, c1_ = 0;
        if (it < 7) {
            int lin0 = t, lin1 = 256 + t;
            r0_ = lin0 >> 3; c0_ = lin0 & 7;
            r1_ = lin1 >> 3; c1_ = lin1 & 7;
            s0 = *(const h8*)(qh + ((size_t)b * Lseq + qbase + (it + 1) * 64 + r0_) * DH + c0_ * 8);
            s1 = *(const h8*)(qh + ((size_t)b * Lseq + qbase + (it + 1) * 64 + r1_) * DH + c1_ * 8);
        }
        const f16* qb = qlds[it & 1];
        __builtin_amdgcn_s_setprio(1);
#pragma unroll
        for (int nt = 0; nt < 4; ++nt) {
            const f16* qp = qb + (nt * 16 + l15) * 72 + quad * 8;
            h8 b0 = *(const h8*)qp;
            h8 b1 = *(const h8*)(qp + 32);
#pragma unroll
            for (int kt = 0; kt < 2; ++kt) {
                f4 c = {0.f, 0.f, 0.f, 0.f};
                c = MFMA(a[kt][0], b0, c);
                c = MFMA(a[kt][1], b1, c);
#pragma unroll
                for (int reg = 0; reg < 4; ++reg) lp[kt][reg] += __expf(c[reg]);
            }
        }
        __builtin_amdgcn_s_setprio(0);
        if (it < 7) {
            f16* qn = qlds[(it & 1) ^ 1];
            *(h8*)(qn + r0_ * 72 + c0_ * 8) = s0;
            *(h8*)(qn + r1_ * 72 + c1_ * 8) = s1;
        }
        __syncthreads();
    }
#pragma unroll
    for (int kt = 0; kt < 2; ++kt)
#pragma unroll
        for (int reg = 0; reg < 4; ++reg) {
            float v = lp[kt][reg];
            v += __shfl_xor(v, 1);
            v += __shfl_xor(v, 2);
            v += __shfl_xor(v, 4);
            v += __shfl_xor(v, 8);
            if (l15 == 0)
                atomicAdd(&lsum[(size_t)b * Lseq + kblk + w * 32 + kt * 16 + quad * 4 + reg], v);
        }
}

// ------- pass 2: S via MFMA, A = exp(s)/lsum -> att (nontemporal stores) + PV ---
__global__ __launch_bounds__(256, 4) void attn_pv(const f16* __restrict__ qh,
                                                  const f16* __restrict__ kh,
                                                  const f16* __restrict__ vt,
                                                  const float* __restrict__ lsum,
                                                  float* __restrict__ att,
                                                  f16* __restrict__ opart) {
    __shared__ __align__(16) f16 klds[2][64 * 72];
    __shared__ __align__(16) f16 es[4][32 * 80];
    int t = threadIdx.x;
    int w = t >> 6, lane = t & 63;
    int l15 = lane & 15, quad = lane >> 4;
    int b = blockIdx.y;
    int q0 = blockIdx.x * 128 + w * 32;
    int split = blockIdx.z;
    int kstart = split * (Lseq / KSPL);

    h8 aq[2][2];
#pragma unroll
    for (int mt = 0; mt < 2; ++mt) {
        const h8* qp = (const h8*)(qh + ((size_t)b * Lseq + q0 + mt * 16 + l15) * DH + quad * 8);
        aq[mt][0] = qp[0];
        aq[mt][1] = qp[4];
    }
    f4 o[2][4];
#pragma unroll
    for (int mt = 0; mt < 2; ++mt)
#pragma unroll
        for (int nt = 0; nt < 4; ++nt) o[mt][nt] = (f4){0.f, 0.f, 0.f, 0.f};

    const float* lsb = lsum + (size_t)b * Lseq;
    f16* ew = es[w];

#pragma unroll
    for (int i = 0; i < 2; ++i) {
        int lin = i * 256 + t;
        int row = lin >> 3, c8 = lin & 7;
        *(h8*)(klds[0] + row * 72 + c8 * 8) =
            *(const h8*)(kh + ((size_t)b * Lseq + kstart + row) * DH + c8 * 8);
    }
    __syncthreads();

    for (int it = 0; it < 8; ++it) {
        int kbase = kstart + it * 64;
        const f16* kb = klds[it & 1];

        h8 s0, s1;
        int r0_ = 0, c0_ = 0, r1_ = 0, c1_ = 0;
        if (it < 7) {
            int lin0 = t, lin1 = 256 + t;
            r0_ = lin0 >> 3; c0_ = lin0 & 7;
            r1_ = lin1 >> 3; c1_ = lin1 & 7;
            s0 = *(const h8*)(kh + ((size_t)b * Lseq + kbase + 64 + r0_) * DH + c0_ * 8);
            s1 = *(const h8*)(kh + ((size_t)b * Lseq + kbase + 64 + r1_) * DH + c1_ * 8);
        }

#pragma unroll
        for (int nt = 0; nt < 4; ++nt) {
            const f16* kp = kb + (nt * 16 + l15) * 72 + quad * 8;
            h8 b0 = *(const h8*)kp;
            h8 b1 = *(const h8*)(kp + 32);
            float rlv = 1.0f / lsb[kbase + nt * 16 + l15];
            __builtin_amdgcn_s_setprio(1);
#pragma unroll
            for (int mt = 0; mt < 2; ++mt) {
                f4 c = {0.f, 0.f, 0.f, 0.f};
                c = MFMA(aq[mt][0], b0, c);
                c = MFMA(aq[mt][1], b1, c);
#pragma unroll
                for (int reg = 0; reg < 4; ++reg)
                    ew[(mt * 16 + quad * 4 + reg) * 80 + nt * 16 + l15] =
                        (f16)(__expf(c[reg]) * rlv);
            }
            __builtin_amdgcn_s_setprio(0);
        }

        {   // att store: nontemporal — keep the 268 MB stream out of L2
            int g = lane >> 3, c8 = lane & 7;
#pragma unroll
            for (int rr = 0; rr < 4; ++rr) {
                int row = rr * 8 + g;
                h8 hv = *(const h8*)(ew + row * 80 + c8 * 8);
                f4 v0, v1;
#pragma unroll
                for (int j = 0; j < 4; ++j) {
                    v0[j] = (float)hv[j];
                    v1[j] = (float)hv[4 + j];
                }
                f4* dst = (f4*)(att + ((size_t)b * Lseq + q0 + row) * Lseq + kbase + c8 * 8);
                __builtin_nontemporal_store(v0, dst);
                __builtin_nontemporal_store(v1, dst + 1);
            }
        }

        h8 ae[2][2];
#pragma unroll
        for (int mt = 0; mt < 2; ++mt) {
            const f16* ep = ew + (mt * 16 + l15) * 80 + quad * 8;
            ae[mt][0] = *(const h8*)ep;
            ae[mt][1] = *(const h8*)(ep + 32);
        }
        __builtin_amdgcn_s_setprio(1);
#pragma unroll
        for (int nt = 0; nt < 4; ++nt) {
            const h8* vp = (const h8*)(vt + ((size_t)b * DH + nt * 16 + l15) * Lseq + kbase + quad * 8);
            h8 bv0 = vp[0];
            h8 bv1 = vp[4];
            o[0][nt] = MFMA(ae[0][0], bv0, o[0][nt]);
            o[0][nt] = MFMA(ae[0][1], bv1, o[0][nt]);
            o[1][nt] = MFMA(ae[1][0], bv0, o[1][nt]);
            o[1][nt] = MFMA(ae[1][1], bv1, o[1][nt]);
        }
        __builtin_amdgcn_s_setprio(0);

        if (it < 7) {
            f16* kn = klds[(it & 1) ^ 1];
            *(h8*)(kn + r0_ * 72 + c0_ * 8) = s0;
            *(h8*)(kn + r1_ * 72 + c1_ * 8) = s1;
        }
        __syncthreads();
    }

#pragma unroll
    for (int mt = 0; mt < 2; ++mt)
#pragma unroll
        for (int nt = 0; nt < 4; ++nt)
#pragma unroll
            for (int reg = 0; reg < 4; ++reg) {
                size_t qrow = (size_t)b * Lseq + q0 + mt * 16 + quad * 4 + reg;
                opart[((size_t)split * BL + qrow) * DH + nt * 16 + l15] = (f16)o[mt][nt][reg];
            }
}

// -------- reduce k-split partials + output projection via split-precision MFMA --
// out = (sum_sp opart) @ Wo + bo ; osum hi/lo staged in LDS; WoT hi/lo from global.
__global__ __launch_bounds__(256) void out_proj(const f16* __restrict__ opart,
                                                const f16* __restrict__ woth,
                                                const f16* __restrict__ wotl,
                                                const float* __restrict__ bo,
                                                float* __restrict__ out) {
    __shared__ __align__(16) f16 osh[64 * 72];
    __shared__ __align__(16) f16 osl[64 * 72];
    int t = threadIdx.x;
    int w = t >> 6, lane = t & 63;
    int l15 = lane & 15, quad = lane >> 4;
    int rg = blockIdx.x;   // 64-row group
    int oq = blockIdx.y;   // 128-col group

    {   // reduce the 8 split partials, hi/lo split, stage [row][d]
        int row = t >> 2, dq = (t & 3) * 16;
        float s[16] = {};
#pragma unroll
        for (int sp = 0; sp < KSPL; ++sp) {
            const h8* src = (const h8*)(opart + ((size_t)sp * BL + (size_t)rg * 64 + row) * DH + dq);
            h8 v0 = src[0], v1 = src[1];
#pragma unroll
            for (int jj = 0; jj < 8; ++jj) {
                s[jj] += (float)v0[jj];
                s[8 + jj] += (float)v1[jj];
            }
        }
        h8 hi0, hi1, lo0, lo1;
#pragma unroll
        for (int jj = 0; jj < 8; ++jj) {
            f16 h0 = (f16)s[jj], h1 = (f16)s[8 + jj];
            hi0[jj] = h0; lo0[jj] = (f16)(s[jj] - (float)h0);
            hi1[jj] = h1; lo1[jj] = (f16)(s[8 + jj] - (float)h1);
        }
        *(h8*)(osh + row * 72 + dq) = hi0;
        *(h8*)(osh + row * 72 + dq + 8) = hi1;
        *(h8*)(osl + row * 72 + dq) = lo0;
        *(h8*)(osl + row * 72 + dq + 8) = lo1;
    }
    __syncthreads();

    // A-frags: wave w owns rows w*16..w*16+16
    int arow = w * 16 + l15;
    h8 ah0 = *(const h8*)(osh + arow * 72 + quad * 8);
    h8 ah1 = *(const h8*)(osh + arow * 72 + 32 + quad * 8);
    h8 al0 = *(const h8*)(osl + arow * 72 + quad * 8);
    h8 al1 = *(const h8*)(osl + arow * 72 + 32 + quad * 8);

    f4 acc[8];
#pragma unroll
    for (int nt = 0; nt < 8; ++nt) acc[nt] = (f4){0.f, 0.f, 0.f, 0.f};

    __builtin_amdgcn_s_setprio(1);
#pragma unroll
    for (int nt = 0; nt < 8; ++nt) {
        int col = oq * 128 + nt * 16 + l15;
        const h8* bh = (const h8*)(woth + (size_t)col * DH + quad * 8);
        const h8* bl = (const h8*)(wotl + (size_t)col * DH + quad * 8);
        h8 bh0 = bh[0], bh1 = bh[4];
        h8 bl0 = bl[0], bl1 = bl[4];
        f4 c = acc[nt];
        c = MFMA(ah0, bh0, c);
        c = MFMA(ah1, bh1, c);
        c = MFMA(al0, bh0, c);
        c = MFMA(al1, bh1, c);
        c = MFMA(ah0, bl0, c);
        c = MFMA(ah1, bl1, c);
        acc[nt] = c;
    }
    __builtin_amdgcn_s_setprio(0);

#pragma unroll
    for (int nt = 0; nt < 8; ++nt) {
        int col = oq * 128 + nt * 16 + l15;
        float bov = bo[col];
#pragma unroll
        for (int reg = 0; reg < 4; ++reg) {
            size_t row = (size_t)rg * 64 + w * 16 + quad * 4 + reg;
            out[row * OUTD + col] = acc[nt][reg] + bov;
        }
    }
}

extern "C" void kernel_launch(void* const* d_in, const int* in_sizes, int n_in,
                              void* d_out, int out_size, void* d_ws, size_t ws_size,
                              hipStream_t stream) {
    const float* x  = (const float*)d_in[0];
    const float* Wq = (const float*)d_in[1];
    const float* bq = (const float*)d_in[2];
    const float* Wk = (const float*)d_in[3];
    const float* bk = (const float*)d_in[4];
    const float* Wv = (const float*)d_in[5];
    const float* bv = (const float*)d_in[6];
    const float* Wo = (const float*)d_in[7];
    const float* bo = (const float*)d_in[8];

    float* out = (float*)d_out;                         // [B,L,OUTD]
    float* att = out + (size_t)BL * OUTD;               // [B,L,L]

    char* ws = (char*)d_ws;
    f16*   qh    = (f16*)(ws + 0);                      // 2 MB
    f16*   kh    = (f16*)(ws + (size_t)(2 << 20));      // 2 MB
    f16*   vt    = (f16*)(ws + (size_t)(4 << 20));      // 2 MB
    float* lsum  = (float*)(ws + (size_t)(6 << 20));    // 64 KB
    f16*   opart = (f16*)(ws + (size_t)(7 << 20));      // 16 MB
    f16*   whi   = (f16*)(ws + (size_t)(23 << 20));     // 192 KB
    f16*   wlo   = (f16*)(ws + (size_t)(23 << 20) + (size_t)(192 << 10)); // 192 KB
    f16*   woth  = (f16*)(ws + (size_t)(23 << 20) + (size_t)(384 << 10)); // 64 KB
    f16*   wotl  = (f16*)(ws + (size_t)(23 << 20) + (size_t)(448 << 10)); // 64 KB

    hipMemsetAsync(lsum, 0, (size_t)BL * sizeof(float), stream);
    wtrans<<<dim3(8, 4), 256, 0, stream>>>(Wq, Wk, Wv, Wo, whi, wlo, woth, wotl);
    proj_qkv<<<dim3(BL / 64), 256, 0, stream>>>(x, whi, wlo, bq, bk, bv, qh, kh, vt);
    col_stats<<<dim3(Lseq / 128, Bdim, QSPL), 256, 0, stream>>>(qh, kh, lsum);
    attn_pv<<<dim3(Lseq / 128, Bdim, KSPL), 256, 0, stream>>>(qh, kh, vt, lsum, att, opart);
    out_proj<<<dim3(BL / 64, OUTD / 128), 256, 0, stream>>>(opart, woth, wotl, bo, out);
}

// Round 8
// 422.887 us; speedup vs baseline: 1.1296x; 1.1296x over previous
//
#include <hip/hip_runtime.h>
#include <hip/hip_fp16.h>
#include <math.h>

#define Bdim 4
#define Lseq 4096
#define INDIM 512
#define DH 64
#define OUTD 512
#define SCALE 0.125f
#define KSPL 8
#define QSPL 8
#define BL (Bdim * Lseq)

typedef _Float16 f16;
typedef _Float16 h8 __attribute__((ext_vector_type(8)));
typedef _Float16 h4 __attribute__((ext_vector_type(4)));
typedef float f4 __attribute__((ext_vector_type(4)));

#define MFMA(a, b, c) __builtin_amdgcn_mfma_f32_16x16x32_f16(a, b, c, 0, 0, 0)

// ------ W pre-transpose + f16 hi/lo split: Wq/Wk/Wv -> [mat][d][k]; Wo -> [o][d] ------
__global__ __launch_bounds__(256) void wtrans(const float* __restrict__ Wq,
                                              const float* __restrict__ Wk,
                                              const float* __restrict__ Wv,
                                              const float* __restrict__ Wo,
                                              f16* __restrict__ whi,
                                              f16* __restrict__ wlo,
                                              f16* __restrict__ woth,
                                              f16* __restrict__ wotl) {
    __shared__ float tile[64 * 68];
    int t = threadIdx.x;
    if (blockIdx.y < 3) {
        int kt = blockIdx.x * 64;
        const float* W = (blockIdx.y == 0) ? Wq : (blockIdx.y == 1) ? Wk : Wv;
        {
            int r = t >> 2, c4 = (t & 3) * 16;
            const float4* src = (const float4*)(W + (size_t)(kt + r) * DH + c4);
#pragma unroll
            for (int i = 0; i < 4; ++i)
                *(float4*)(tile + r * 68 + c4 + 4 * i) = src[i];
        }
        __syncthreads();
        {
            int d = t >> 2, k8 = (t & 3) * 16;
            h8 hi0, hi1, lo0, lo1;
#pragma unroll
            for (int j = 0; j < 8; ++j) {
                float v0 = tile[(k8 + j) * 68 + d];
                float v1 = tile[(k8 + 8 + j) * 68 + d];
                f16 h0 = (f16)v0, h1 = (f16)v1;
                hi0[j] = h0; lo0[j] = (f16)(v0 - (float)h0);
                hi1[j] = h1; lo1[j] = (f16)(v1 - (float)h1);
            }
            size_t base = ((size_t)blockIdx.y * DH + d) * INDIM + kt + k8;
            *(h8*)(whi + base) = hi0;
            *(h8*)(whi + base + 8) = hi1;
            *(h8*)(wlo + base) = lo0;
            *(h8*)(wlo + base + 8) = lo1;
        }
    } else {
        // Wo [64 d][512 o] -> WoT hi/lo [o][d], o-chunk = blockIdx.x*64
        int o0 = blockIdx.x * 64;
        {
            int d = t >> 2, o4 = (t & 3) * 16;
            const float4* src = (const float4*)(Wo + (size_t)d * OUTD + o0 + o4);
#pragma unroll
            for (int i = 0; i < 4; ++i)
                *(float4*)(tile + d * 68 + o4 + 4 * i) = src[i];
        }
        __syncthreads();
        {
            int o = t >> 2, d8 = (t & 3) * 16;
            h8 hi0, hi1, lo0, lo1;
#pragma unroll
            for (int j = 0; j < 8; ++j) {
                float v0 = tile[(d8 + j) * 68 + o];
                float v1 = tile[(d8 + 8 + j) * 68 + o];
                f16 h0 = (f16)v0, h1 = (f16)v1;
                hi0[j] = h0; lo0[j] = (f16)(v0 - (float)h0);
                hi1[j] = h1; lo1[j] = (f16)(v1 - (float)h1);
            }
            size_t base = (size_t)(o0 + o) * DH + d8;
            *(h8*)(woth + base) = hi0;
            *(h8*)(woth + base + 8) = hi1;
            *(h8*)(wotl + base) = lo0;
            *(h8*)(wotl + base + 8) = lo1;
        }
    }
}

// ---------------- fused q/k/v projection via split-precision f16 MFMA ----------
__global__ __launch_bounds__(256) void proj_qkv(const float* __restrict__ x,
                                                const f16* __restrict__ whi,
                                                const f16* __restrict__ wlo,
                                                const float* __restrict__ bq,
                                                const float* __restrict__ bk,
                                                const float* __restrict__ bv,
                                                f16* __restrict__ qh,
                                                f16* __restrict__ kh,
                                                f16* __restrict__ vt) {
    __shared__ __align__(16) f16 xh[64 * 72];
    __shared__ __align__(16) f16 xl[64 * 72];
    __shared__ __align__(16) f16 wl[6][64 * 72];   // [mat*2 + hilo][d][k]
    int t = threadIdx.x;
    int w = t >> 6, lane = t & 63;
    int l15 = lane & 15, quad = lane >> 4;
    size_t row0 = (size_t)blockIdx.x * 64;

    int xr = t >> 2, xkq = (t & 3) * 16;
    int wd = t >> 2, wko = (t & 3) * 16;

    f4 acc[3][4];
#pragma unroll
    for (int m = 0; m < 3; ++m)
#pragma unroll
        for (int nt = 0; nt < 4; ++nt) acc[m][nt] = (f4){0.f, 0.f, 0.f, 0.f};

    f4 xs[4];
    h8 wsr[12];

#define PROJ_ISSUE(kc)                                                             \
    {                                                                              \
        const f4* xsrc = (const f4*)(x + (row0 + xr) * INDIM + (kc) + xkq);        \
        _Pragma("unroll") for (int i = 0; i < 4; ++i) xs[i] = xsrc[i];             \
        _Pragma("unroll") for (int p = 0; p < 6; ++p) {                            \
            const f16* src = ((p & 1) ? wlo : whi) +                               \
                             ((size_t)(p >> 1) * DH + wd) * INDIM + (kc) + wko;    \
            wsr[p * 2] = *(const h8*)src;                                          \
            wsr[p * 2 + 1] = *(const h8*)(src + 8);                                \
        }                                                                          \
    }

#define PROJ_COMMIT()                                                              \
    {                                                                              \
        h8 hi0, hi1, lo0, lo1;                                                     \
        _Pragma("unroll") for (int j = 0; j < 8; ++j) {                            \
            float v0 = ((const float*)xs)[j];                                      \
            float v1 = ((const float*)xs)[8 + j];                                  \
            f16 h0 = (f16)v0, h1 = (f16)v1;                                        \
            hi0[j] = h0; lo0[j] = (f16)(v0 - (float)h0);                           \
            hi1[j] = h1; lo1[j] = (f16)(v1 - (float)h1);                           \
        }                                                                          \
        *(h8*)(xh + xr * 72 + xkq) = hi0;                                          \
        *(h8*)(xh + xr * 72 + xkq + 8) = hi1;                                      \
        *(h8*)(xl + xr * 72 + xkq) = lo0;                                          \
        *(h8*)(xl + xr * 72 + xkq + 8) = lo1;                                      \
        _Pragma("unroll") for (int p = 0; p < 6; ++p) {                            \
            *(h8*)(wl[p] + wd * 72 + wko) = wsr[p * 2];                            \
            *(h8*)(wl[p] + wd * 72 + wko + 8) = wsr[p * 2 + 1];                    \
        }                                                                          \
    }

    PROJ_ISSUE(0);
    PROJ_COMMIT();
    __syncthreads();

    int arow = w * 16 + l15;
    for (int it = 0; it < 8; ++it) {
        if (it < 7) PROJ_ISSUE((it + 1) * 64);

        h8 ah0 = *(const h8*)(xh + arow * 72 + quad * 8);
        h8 ah1 = *(const h8*)(xh + arow * 72 + 32 + quad * 8);
        h8 al0 = *(const h8*)(xl + arow * 72 + quad * 8);
        h8 al1 = *(const h8*)(xl + arow * 72 + 32 + quad * 8);
#pragma unroll
        for (int m = 0; m < 3; ++m) {
            const f16* bh = wl[m * 2];
            const f16* bl = wl[m * 2 + 1];
#pragma unroll
            for (int nt = 0; nt < 4; ++nt) {
                int d = nt * 16 + l15;
                h8 bh0 = *(const h8*)(bh + d * 72 + quad * 8);
                h8 bh1 = *(const h8*)(bh + d * 72 + 32 + quad * 8);
                h8 bl0 = *(const h8*)(bl + d * 72 + quad * 8);
                h8 bl1 = *(const h8*)(bl + d * 72 + 32 + quad * 8);
                f4 c = acc[m][nt];
                c = MFMA(ah0, bh0, c);
                c = MFMA(ah1, bh1, c);
                c = MFMA(al0, bh0, c);
                c = MFMA(al1, bh1, c);
                c = MFMA(ah0, bl0, c);
                c = MFMA(ah1, bl1, c);
                acc[m][nt] = c;
            }
        }
        __syncthreads();
        if (it < 7) PROJ_COMMIT();
        __syncthreads();
    }

    int b = (int)(row0 >> 12);
    int kr0 = ((int)row0 & (Lseq - 1)) + w * 16 + quad * 4;
#pragma unroll
    for (int nt = 0; nt < 4; ++nt) {
        int d = nt * 16 + l15;
        float bqv = bq[d], bkv = bk[d], bvv = bv[d];
#pragma unroll
        for (int reg = 0; reg < 4; ++reg) {
            size_t r = row0 + w * 16 + quad * 4 + reg;
            qh[r * DH + d] = (f16)((acc[0][nt][reg] + bqv) * SCALE);
            kh[r * DH + d] = (f16)(acc[1][nt][reg] + bkv);
        }
        h4 pv;
#pragma unroll
        for (int reg = 0; reg < 4; ++reg) pv[reg] = (f16)(acc[2][nt][reg] + bvv);
        *(h4*)(vt + ((size_t)b * DH + d) * Lseq + kr0) = pv;
    }
#undef PROJ_ISSUE
#undef PROJ_COMMIT
}

// ---------------- pass 1: column sums of exp(s) via MFMA (D = K·Q^T) ------------
__global__ __launch_bounds__(256) void col_stats(const f16* __restrict__ qh,
                                                 const f16* __restrict__ kh,
                                                 float* __restrict__ lsum) {
    __shared__ __align__(16) f16 qlds[2][64 * 72];
    int t = threadIdx.x;
    int w = t >> 6, lane = t & 63;
    int l15 = lane & 15, quad = lane >> 4;
    int b = blockIdx.y;
    int kblk = blockIdx.x * 128;
    int qbase = blockIdx.z * (Lseq / QSPL);

    h8 a[2][2];
#pragma unroll
    for (int kt = 0; kt < 2; ++kt) {
        const h8* kr = (const h8*)(kh + ((size_t)b * Lseq + kblk + w * 32 + kt * 16 + l15) * DH + quad * 8);
        a[kt][0] = kr[0];
        a[kt][1] = kr[4];
    }
    float lp[2][4] = {};

#pragma unroll
    for (int i = 0; i < 2; ++i) {
        int lin = i * 256 + t;
        int row = lin >> 3, c8 = lin & 7;
        *(h8*)(qlds[0] + row * 72 + c8 * 8) =
            *(const h8*)(qh + ((size_t)b * Lseq + qbase + row) * DH + c8 * 8);
    }
    __syncthreads();

    for (int it = 0; it < (Lseq / QSPL) / 64; ++it) {
        h8 s0, s1;
        int r0_ = 0, c0_ = 0, r1_ = 0, c1_ = 0;
        if (it < 7) {
            int lin0 = t, lin1 = 256 + t;
            r0_ = lin0 >> 3; c0_ = lin0 & 7;
            r1_ = lin1 >> 3; c1_ = lin1 & 7;
            s0 = *(const h8*)(qh + ((size_t)b * Lseq + qbase + (it + 1) * 64 + r0_) * DH + c0_ * 8);
            s1 = *(const h8*)(qh + ((size_t)b * Lseq + qbase + (it + 1) * 64 + r1_) * DH + c1_ * 8);
        }
        const f16* qb = qlds[it & 1];
        __builtin_amdgcn_s_setprio(1);
#pragma unroll
        for (int nt = 0; nt < 4; ++nt) {
            const f16* qp = qb + (nt * 16 + l15) * 72 + quad * 8;
            h8 b0 = *(const h8*)qp;
            h8 b1 = *(const h8*)(qp + 32);
#pragma unroll
            for (int kt = 0; kt < 2; ++kt) {
                f4 c = {0.f, 0.f, 0.f, 0.f};
                c = MFMA(a[kt][0], b0, c);
                c = MFMA(a[kt][1], b1, c);
#pragma unroll
                for (int reg = 0; reg < 4; ++reg) lp[kt][reg] += __expf(c[reg]);
            }
        }
        __builtin_amdgcn_s_setprio(0);
        if (it < 7) {
            f16* qn = qlds[(it & 1) ^ 1];
            *(h8*)(qn + r0_ * 72 + c0_ * 8) = s0;
            *(h8*)(qn + r1_ * 72 + c1_ * 8) = s1;
        }
        __syncthreads();
    }
#pragma unroll
    for (int kt = 0; kt < 2; ++kt)
#pragma unroll
        for (int reg = 0; reg < 4; ++reg) {
            float v = lp[kt][reg];
            v += __shfl_xor(v, 1);
            v += __shfl_xor(v, 2);
            v += __shfl_xor(v, 4);
            v += __shfl_xor(v, 8);
            if (l15 == 0)
                atomicAdd(&lsum[(size_t)b * Lseq + kblk + w * 32 + kt * 16 + quad * 4 + reg], v);
        }
}

// ------- pass 2: S via MFMA, A = exp(s)/lsum -> att (full-line stores) + PV -----
__global__ __launch_bounds__(256, 4) void attn_pv(const f16* __restrict__ qh,
                                                  const f16* __restrict__ kh,
                                                  const f16* __restrict__ vt,
                                                  const float* __restrict__ lsum,
                                                  float* __restrict__ att,
                                                  f16* __restrict__ opart) {
    __shared__ __align__(16) f16 klds[2][64 * 72];
    __shared__ __align__(16) f16 es[4][32 * 80];
    int t = threadIdx.x;
    int w = t >> 6, lane = t & 63;
    int l15 = lane & 15, quad = lane >> 4;
    int b = blockIdx.y;
    int q0 = blockIdx.x * 128 + w * 32;
    int split = blockIdx.z;
    int kstart = split * (Lseq / KSPL);

    h8 aq[2][2];
#pragma unroll
    for (int mt = 0; mt < 2; ++mt) {
        const h8* qp = (const h8*)(qh + ((size_t)b * Lseq + q0 + mt * 16 + l15) * DH + quad * 8);
        aq[mt][0] = qp[0];
        aq[mt][1] = qp[4];
    }
    f4 o[2][4];
#pragma unroll
    for (int mt = 0; mt < 2; ++mt)
#pragma unroll
        for (int nt = 0; nt < 4; ++nt) o[mt][nt] = (f4){0.f, 0.f, 0.f, 0.f};

    const float* lsb = lsum + (size_t)b * Lseq;
    f16* ew = es[w];

#pragma unroll
    for (int i = 0; i < 2; ++i) {
        int lin = i * 256 + t;
        int row = lin >> 3, c8 = lin & 7;
        *(h8*)(klds[0] + row * 72 + c8 * 8) =
            *(const h8*)(kh + ((size_t)b * Lseq + kstart + row) * DH + c8 * 8);
    }
    __syncthreads();

    for (int it = 0; it < 8; ++it) {
        int kbase = kstart + it * 64;
        const f16* kb = klds[it & 1];

        h8 s0, s1;
        int r0_ = 0, c0_ = 0, r1_ = 0, c1_ = 0;
        if (it < 7) {
            int lin0 = t, lin1 = 256 + t;
            r0_ = lin0 >> 3; c0_ = lin0 & 7;
            r1_ = lin1 >> 3; c1_ = lin1 & 7;
            s0 = *(const h8*)(kh + ((size_t)b * Lseq + kbase + 64 + r0_) * DH + c0_ * 8);
            s1 = *(const h8*)(kh + ((size_t)b * Lseq + kbase + 64 + r1_) * DH + c1_ * 8);
        }

#pragma unroll
        for (int nt = 0; nt < 4; ++nt) {
            const f16* kp = kb + (nt * 16 + l15) * 72 + quad * 8;
            h8 b0 = *(const h8*)kp;
            h8 b1 = *(const h8*)(kp + 32);
            float rlv = 1.0f / lsb[kbase + nt * 16 + l15];
            __builtin_amdgcn_s_setprio(1);
#pragma unroll
            for (int mt = 0; mt < 2; ++mt) {
                f4 c = {0.f, 0.f, 0.f, 0.f};
                c = MFMA(aq[mt][0], b0, c);
                c = MFMA(aq[mt][1], b1, c);
#pragma unroll
                for (int reg = 0; reg < 4; ++reg)
                    ew[(mt * 16 + quad * 4 + reg) * 80 + nt * 16 + l15] =
                        (f16)(__expf(c[reg]) * rlv);
            }
            __builtin_amdgcn_s_setprio(0);
        }

        {
            int g = lane >> 3, c8 = lane & 7;
#pragma unroll
            for (int rr = 0; rr < 4; ++rr) {
                int row = rr * 8 + g;
                h8 hv = *(const h8*)(ew + row * 80 + c8 * 8);
                f4 v0, v1;
#pragma unroll
                for (int j = 0; j < 4; ++j) {
                    v0[j] = (float)hv[j];
                    v1[j] = (float)hv[4 + j];
                }
                float* dst = att + ((size_t)b * Lseq + q0 + row) * Lseq + kbase + c8 * 8;
                *(f4*)dst = v0;
                *(f4*)(dst + 4) = v1;
            }
        }

        h8 ae[2][2];
#pragma unroll
        for (int mt = 0; mt < 2; ++mt) {
            const f16* ep = ew + (mt * 16 + l15) * 80 + quad * 8;
            ae[mt][0] = *(const h8*)ep;
            ae[mt][1] = *(const h8*)(ep + 32);
        }
        __builtin_amdgcn_s_setprio(1);
#pragma unroll
        for (int nt = 0; nt < 4; ++nt) {
            const h8* vp = (const h8*)(vt + ((size_t)b * DH + nt * 16 + l15) * Lseq + kbase + quad * 8);
            h8 bv0 = vp[0];
            h8 bv1 = vp[4];
            o[0][nt] = MFMA(ae[0][0], bv0, o[0][nt]);
            o[0][nt] = MFMA(ae[0][1], bv1, o[0][nt]);
            o[1][nt] = MFMA(ae[1][0], bv0, o[1][nt]);
            o[1][nt] = MFMA(ae[1][1], bv1, o[1][nt]);
        }
        __builtin_amdgcn_s_setprio(0);

        if (it < 7) {
            f16* kn = klds[(it & 1) ^ 1];
            *(h8*)(kn + r0_ * 72 + c0_ * 8) = s0;
            *(h8*)(kn + r1_ * 72 + c1_ * 8) = s1;
        }
        __syncthreads();
    }

#pragma unroll
    for (int mt = 0; mt < 2; ++mt)
#pragma unroll
        for (int nt = 0; nt < 4; ++nt)
#pragma unroll
            for (int reg = 0; reg < 4; ++reg) {
                size_t qrow = (size_t)b * Lseq + q0 + mt * 16 + quad * 4 + reg;
                opart[((size_t)split * BL + qrow) * DH + nt * 16 + l15] = (f16)o[mt][nt][reg];
            }
}

// -------- reduce k-split partials + output projection via split-precision MFMA --
// out = (sum_sp opart) @ Wo + bo ; osum hi/lo staged in LDS; WoT hi/lo from global.
__global__ __launch_bounds__(256) void out_proj(const f16* __restrict__ opart,
                                                const f16* __restrict__ woth,
                                                const f16* __restrict__ wotl,
                                                const float* __restrict__ bo,
                                                float* __restrict__ out) {
    __shared__ __align__(16) f16 osh[64 * 72];
    __shared__ __align__(16) f16 osl[64 * 72];
    int t = threadIdx.x;
    int w = t >> 6, lane = t & 63;
    int l15 = lane & 15, quad = lane >> 4;
    int rg = blockIdx.x;   // 64-row group
    int oq = blockIdx.y;   // 128-col group

    {   // reduce the 8 split partials, hi/lo split, stage [row][d]
        int row = t >> 2, dq = (t & 3) * 16;
        float s[16] = {};
#pragma unroll
        for (int sp = 0; sp < KSPL; ++sp) {
            const h8* src = (const h8*)(opart + ((size_t)sp * BL + (size_t)rg * 64 + row) * DH + dq);
            h8 v0 = src[0], v1 = src[1];
#pragma unroll
            for (int jj = 0; jj < 8; ++jj) {
                s[jj] += (float)v0[jj];
                s[8 + jj] += (float)v1[jj];
            }
        }
        h8 hi0, hi1, lo0, lo1;
#pragma unroll
        for (int jj = 0; jj < 8; ++jj) {
            f16 h0 = (f16)s[jj], h1 = (f16)s[8 + jj];
            hi0[jj] = h0; lo0[jj] = (f16)(s[jj] - (float)h0);
            hi1[jj] = h1; lo1[jj] = (f16)(s[8 + jj] - (float)h1);
        }
        *(h8*)(osh + row * 72 + dq) = hi0;
        *(h8*)(osh + row * 72 + dq + 8) = hi1;
        *(h8*)(osl + row * 72 + dq) = lo0;
        *(h8*)(osl + row * 72 + dq + 8) = lo1;
    }
    __syncthreads();

    // A-frags: wave w owns rows w*16..w*16+16
    int arow = w * 16 + l15;
    h8 ah0 = *(const h8*)(osh + arow * 72 + quad * 8);
    h8 ah1 = *(const h8*)(osh + arow * 72 + 32 + quad * 8);
    h8 al0 = *(const h8*)(osl + arow * 72 + quad * 8);
    h8 al1 = *(const h8*)(osl + arow * 72 + 32 + quad * 8);

    f4 acc[8];
#pragma unroll
    for (int nt = 0; nt < 8; ++nt) acc[nt] = (f4){0.f, 0.f, 0.f, 0.f};

    __builtin_amdgcn_s_setprio(1);
#pragma unroll
    for (int nt = 0; nt < 8; ++nt) {
        int col = oq * 128 + nt * 16 + l15;
        const h8* bh = (const h8*)(woth + (size_t)col * DH + quad * 8);
        const h8* bl = (const h8*)(wotl + (size_t)col * DH + quad * 8);
        h8 bh0 = bh[0], bh1 = bh[4];
        h8 bl0 = bl[0], bl1 = bl[4];
        f4 c = acc[nt];
        c = MFMA(ah0, bh0, c);
        c = MFMA(ah1, bh1, c);
        c = MFMA(al0, bh0, c);
        c = MFMA(al1, bh1, c);
        c = MFMA(ah0, bl0, c);
        c = MFMA(ah1, bl1, c);
        acc[nt] = c;
    }
    __builtin_amdgcn_s_setprio(0);

#pragma unroll
    for (int nt = 0; nt < 8; ++nt) {
        int col = oq * 128 + nt * 16 + l15;
        float bov = bo[col];
#pragma unroll
        for (int reg = 0; reg < 4; ++reg) {
            size_t row = (size_t)rg * 64 + w * 16 + quad * 4 + reg;
            out[row * OUTD + col] = acc[nt][reg] + bov;
        }
    }
}

extern "C" void kernel_launch(void* const* d_in, const int* in_sizes, int n_in,
                              void* d_out, int out_size, void* d_ws, size_t ws_size,
                              hipStream_t stream) {
    const float* x  = (const float*)d_in[0];
    const float* Wq = (const float*)d_in[1];
    const float* bq = (const float*)d_in[2];
    const float* Wk = (const float*)d_in[3];
    const float* bk = (const float*)d_in[4];
    const float* Wv = (const float*)d_in[5];
    const float* bv = (const float*)d_in[6];
    const float* Wo = (const float*)d_in[7];
    const float* bo = (const float*)d_in[8];

    float* out = (float*)d_out;                         // [B,L,OUTD]
    float* att = out + (size_t)BL * OUTD;               // [B,L,L]

    char* ws = (char*)d_ws;
    f16*   qh    = (f16*)(ws + 0);                      // 2 MB
    f16*   kh    = (f16*)(ws + (size_t)(2 << 20));      // 2 MB
    f16*   vt    = (f16*)(ws + (size_t)(4 << 20));      // 2 MB
    float* lsum  = (float*)(ws + (size_t)(6 << 20));    // 64 KB
    f16*   opart = (f16*)(ws + (size_t)(7 << 20));      // 16 MB
    f16*   whi   = (f16*)(ws + (size_t)(23 << 20));     // 192 KB
    f16*   wlo   = (f16*)(ws + (size_t)(23 << 20) + (size_t)(192 << 10)); // 192 KB
    f16*   woth  = (f16*)(ws + (size_t)(23 << 20) + (size_t)(384 << 10)); // 64 KB
    f16*   wotl  = (f16*)(ws + (size_t)(23 << 20) + (size_t)(448 << 10)); // 64 KB

    hipMemsetAsync(lsum, 0, (size_t)BL * sizeof(float), stream);
    wtrans<<<dim3(8, 4), 256, 0, stream>>>(Wq, Wk, Wv, Wo, whi, wlo, woth, wotl);
    proj_qkv<<<dim3(BL / 64), 256, 0, stream>>>(x, whi, wlo, bq, bk, bv, qh, kh, vt);
    col_stats<<<dim3(Lseq / 128, Bdim, QSPL), 256, 0, stream>>>(qh, kh, lsum);
    attn_pv<<<dim3(Lseq / 128, Bdim, KSPL), 256, 0, stream>>>(qh, kh, vt, lsum, att, opart);
    out_proj<<<dim3(BL / 64, OUTD / 128), 256, 0, stream>>>(opart, woth, wotl, bo, out);
}